// Round 3
// baseline (81.497 us; speedup 1.0000x reference)
//
#include <hip/hip_runtime.h>
#include <math.h>

#define N_BOX   256
#define M_PTS   512
#define S_SPLIT 16                   // m2-range splits per box
#define BLK     64                   // 1 wave per block
#define R_ROWS  8                    // m1 rows per thread (BLK*R_ROWS = M_PTS)
#define M2_PER  (M_PTS / S_SPLIT)    // 32 m2 per block
#define GRID    (N_BOX * S_SPLIT)    // 4096 blocks -> 16 blocks/CU = 4 waves/SIMD

// Each block: box n = blockIdx>>4, m2 slice s = blockIdx&15 (m2 in [32s,32s+32)).
// Thread t owns m1 rows {t + 64*r, r=0..7}. Inner loop is the minimal
// 4 fma + 1 exp per (m1,m2) element:
//   s = nG + Gx2*mx + Gy2*my           (|G-m|^2 expanded; |m|^2 folded into LDS weights)
//   e = exp2(s);  az += e*pz;  aw += e*pw
__global__ __launch_bounds__(BLK, 4) void loss_main(
    const float* __restrict__ pred,    // (N,5)
    const float* __restrict__ target,  // (N,5)
    const float* __restrict__ mask,    // (N,M,2)
    const float* __restrict__ gradx,   // (N,M)
    const float* __restrict__ grady,   // (N,M)
    const float* __restrict__ offset,  // (N,2)
    float* __restrict__ part)          // (GRID,) partial sums
{
    __shared__ float4 sPack[M2_PER];   // {mx, my, gvx*B', gvy*B'}, B' = B*exp2(c1*|m|^2)

    const int n = blockIdx.x >> 4;
    const int s = blockIdx.x & 15;
    const int t = threadIdx.x;

    const float offx = offset[n * 2 + 0];
    const float offy = offset[n * 2 + 1];
    const float px = pred[n * 5 + 0] - offx;
    const float py = pred[n * 5 + 1] - offy;
    const float pw = pred[n * 5 + 2];
    const float ph = pred[n * 5 + 3];
    const float pa = pred[n * 5 + 4];
    const float gx = target[n * 5 + 0] - offx;
    const float gy = target[n * 5 + 1] - offy;
    const float gw = target[n * 5 + 2];
    const float gh = target[n * 5 + 3];
    const float ga = target[n * 5 + 4];

    float sinpa, cospa, singa, cosga;
    sincosf(pa, &sinpa, &cospa);
    sincosf(ga, &singa, &cosga);

    const float THETA2   = 400.0f;
    const float LOG2E    = 1.4426950408889634f;
    const float c1       = LOG2E / (2.0f * THETA2 * THETA2);   // exp2 scale on dist^2
    const float n2c1     = -2.0f * c1;
    const float inv_norm = 1.0f / (2.0f * (float)M_PI * THETA2);

    const float pwg = pw / gw, phg = ph / gh;
    const float cwx = pwg * cospa, swx = pwg * sinpa;
    const float chx = phg * cospa, shx = phg * sinpa;
    const float absinga = fabsf(singa);
    const float kA  = 15.0f * LOG2E / gw;
    const float kH  = 15.0f * LOG2E / gh;
    const float kB  = 15.0f * LOG2E;
    const bool  gaPos = (ga > 0.0f), gaNeg = (ga < 0.0f);

    const float2* mask2 = (const float2*)mask;
    const size_t  baseM = (size_t)n * M_PTS;

    float Gx2[R_ROWS], Gy2[R_ROWS], nG[R_ROWS], gvxr[R_ROWS], gvyr[R_ROWS];

    // ---- phase 1: per-row geometry via rotation identity (no acos/sincos/sqrt) ----
    const int  rStore = s >> 1;
    const bool tMatch = ((t >> 5) == (s & 1));
#pragma unroll
    for (int r = 0; r < R_ROWS; ++r) {
        const int    m  = t + (r << 6);
        const float2 mp = mask2[baseM + m];
        const float dx = mp.x - gx;
        const float dy = mp.y - gy;
        const float u = singa * dy - cosga * dx;      // d*cos(beta)
        const float v = -(cosga * dy + singa * dx);   // d*sin(beta)
        const bool sgaOk = gaPos ? (dy <= 0.0f) : (gaNeg ? (dy > 0.0f) : false);
        const bool wrap  = sgaOk && (dx > 0.0f) && (dx * absinga > fabsf(dy) * cosga);
        const float au = fabsf(u), av = fabsf(v);     // d_w, d_h
        const float dws = (wrap || v > 0.0f) ? -au : au;
        const float dhs = (wrap || u > 0.0f) ? -av : av;
        const float Gx = px + dws * cwx - dhs * shx;  // gaussian center
        const float Gy = py + dws * swx + dhs * chx;
        const float gvx = gradx[baseM + m];
        const float gvy = grady[baseM + m];
        Gx2[r]  = n2c1 * Gx;
        Gy2[r]  = n2c1 * Gy;
        nG[r]   = c1 * fmaf(Gx, Gx, Gy * Gy);
        gvxr[r] = gvx;
        gvyr[r] = gvy;
        if (tMatch && r == rStore) {
            // (1-sig(x))(1-sig(y)) = 1/((1+e^x)(1+e^y)); fold exp2(c1*|m|^2) in
            const float eA = __builtin_amdgcn_exp2f(fmaf(au, kA, -kB));
            const float eB = __builtin_amdgcn_exp2f(fmaf(av, kH, -kB));
            const float m2n = c1 * fmaf(mp.x, mp.x, mp.y * mp.y);  // <= ~2.4
            const float B  = inv_norm * __builtin_amdgcn_exp2f(m2n)
                             / ((1.0f + eA) * (1.0f + eB));
            sPack[t & 31] = make_float4(mp.x, mp.y, gvx * B, gvy * B);
        }
    }
    __syncthreads();

    // ---- phase 2: 4 fma + 1 exp per element ----
    float az[R_ROWS], aw[R_ROWS];
#pragma unroll
    for (int r = 0; r < R_ROWS; ++r) { az[r] = 0.0f; aw[r] = 0.0f; }

#pragma unroll 4
    for (int m2 = 0; m2 < M2_PER; ++m2) {
        const float4 p = sPack[m2];
#pragma unroll
        for (int r = 0; r < R_ROWS; ++r) {
            const float sv = fmaf(Gx2[r], p.x, fmaf(Gy2[r], p.y, nG[r]));
            const float e  = __builtin_amdgcn_exp2f(sv);
            az[r] = fmaf(e, p.z, az[r]);
            aw[r] = fmaf(e, p.w, aw[r]);
        }
    }

    // w-term factorization: sum w*e = gvx*sum(z*e) + gvy*sum(w*e)
    float acc = 0.0f;
#pragma unroll
    for (int r = 0; r < R_ROWS; ++r)
        acc += fmaf(gvxr[r], az[r], gvyr[r] * aw[r]);

#pragma unroll
    for (int off = 32; off > 0; off >>= 1)
        acc += __shfl_down(acc, off, 64);
    if (t == 0) part[blockIdx.x] = acc;
}

__global__ __launch_bounds__(256) void loss_reduce(const float* __restrict__ part,
                                                   float* __restrict__ out)
{
    __shared__ float sW[4];
    const int t = threadIdx.x;
    const float4* p4 = (const float4*)part;            // 4096 floats = 1024 float4
    float acc = 0.0f;
#pragma unroll
    for (int j = 0; j < 4; ++j) {
        const float4 a = p4[t + 256 * j];
        acc += ((a.x + a.y) + (a.z + a.w));
    }
#pragma unroll
    for (int off = 32; off > 0; off >>= 1)
        acc += __shfl_down(acc, off, 64);
    if ((t & 63) == 0) sW[t >> 6] = acc;
    __syncthreads();
    if (t == 0) {
        const float scale = 1.0f / ((float)N_BOX * (float)M_PTS * (float)M_PTS);
        out[0] = (sW[0] + sW[1] + sW[2] + sW[3]) * scale;
    }
}

extern "C" void kernel_launch(void* const* d_in, const int* in_sizes, int n_in,
                              void* d_out, int out_size, void* d_ws, size_t ws_size,
                              hipStream_t stream) {
    const float* pred   = (const float*)d_in[0];
    const float* target = (const float*)d_in[1];
    const float* mask   = (const float*)d_in[2];
    const float* gradx  = (const float*)d_in[3];
    const float* grady  = (const float*)d_in[4];
    const float* offset = (const float*)d_in[5];
    float* out  = (float*)d_out;
    float* part = (float*)d_ws;   // 4096 floats of scratch

    hipLaunchKernelGGL(loss_main, dim3(GRID), dim3(BLK), 0, stream,
                       pred, target, mask, gradx, grady, offset, part);
    hipLaunchKernelGGL(loss_reduce, dim3(1), dim3(256), 0, stream, part, out);
}